// Round 6
// baseline (643.088 us; speedup 1.0000x reference)
//
#include <hip/hip_runtime.h>

#define NE 32
#define NT 2048
#define NH 1024
#define NI 512
#define NK 4
#define CAP 512

typedef __attribute__((ext_vector_type(8))) short short8;
typedef __attribute__((ext_vector_type(4))) float floatx4;

// ---- fp32 -> bf16 (RNE) pair pack -> one dword ----
static __device__ __forceinline__ unsigned pk_bf16(float x, float y) {
#if __has_builtin(__builtin_amdgcn_cvt_pk_bf16_f32)
    typedef __attribute__((ext_vector_type(2))) __bf16 bf16x2;
    union { bf16x2 v; unsigned u; } c;
    c.v = __builtin_amdgcn_cvt_pk_bf16_f32(x, y);
    return c.u;
#else
    union { float f; unsigned u; } a, b;
    a.f = x; b.f = y;
    unsigned ua = (a.u + 0x7fffu + ((a.u >> 16) & 1u)) >> 16;
    unsigned ub = (b.u + 0x7fffu + ((b.u >> 16) & 1u)) >> 16;
    return (ua & 0xffffu) | (ub << 16);
#endif
}

static __device__ __forceinline__ unsigned short bf16_1(float x) {
    return (unsigned short)(pk_bf16(x, 0.f) & 0xffffu);
}

// build a bf16 B-fragment from 8 consecutive fp32 (two float4 loads already done)
static __device__ __forceinline__ short8 cvt_frag(float4 lo, float4 hi) {
    union { unsigned u[4]; short8 s; } c;
    c.u[0] = pk_bf16(lo.x, lo.y);
    c.u[1] = pk_bf16(lo.z, lo.w);
    c.u[2] = pk_bf16(hi.x, hi.y);
    c.u[3] = pk_bf16(hi.z, hi.w);
    return c.s;
}

// ---------------- routing ----------------
__global__ void route_kernel(const int* __restrict__ idx,
                             const float* __restrict__ w,
                             int* __restrict__ counts,
                             int* __restrict__ tok,
                             float* __restrict__ wgt) {
    int tid = blockIdx.x * blockDim.x + threadIdx.x;
    if (tid >= NT * NK) return;
    int e = idx[tid];
    int pos = atomicAdd(&counts[e], 1);
    if (pos < CAP) {
        tok[e * CAP + pos] = tid;          // tid = t*NK + k
        wgt[e * CAP + pos] = w[tid];
    }
}

// ---------------- hidden fp32 -> bf16 (4 MB, one cheap pass) ----------------
__global__ void cvt_hidden(const float* __restrict__ hidden,
                           unsigned short* __restrict__ hb16) {
    size_t o = (size_t)(blockIdx.x * 256 + threadIdx.x) * 8;
    float4 a = *(const float4*)(hidden + o);
    float4 b = *(const float4*)(hidden + o + 4);
    *(short8*)(hb16 + o) = cvt_frag(a, b);
}

// ================= LDS-free direct-fragment MFMA GEMMs =================
// MFMA 16x16x32 A/B fragment: lane holds row (lane&15), k = (lane>>4)*8 .. +7
// => one 16B global load per fragment from row-major [row][k] data.
// No LDS, no barriers: waves fully independent, latency hidden by occupancy.

// ---------------- gate/up + SiLU ----------------
// block tile: 128 entries x 64 j. wave (wm,wj): 64 entries x 32 j.
// Per wave: A-frags mt0..3 (rows), B-frags nt0,1 = gate j, nt2,3 = up j (in-reg SiLU).
__global__ __launch_bounds__(256, 3) void gateup_mfma(
    const unsigned short* __restrict__ hb16,   // [NT][NH] bf16
    const float* __restrict__ gup,             // [NE][2*NI][NH] fp32
    const int* __restrict__ counts,
    const int* __restrict__ tok,
    unsigned short* __restrict__ hbuf)         // [NT*NK][NI] bf16
{
    int e = blockIdx.z;
    int cnt = counts[e]; if (cnt > CAP) cnt = CAP;
    int m0 = blockIdx.y * 128;
    if (m0 >= cnt) return;
    int j0 = blockIdx.x * 64;

    int tid = threadIdx.x;
    int wave = tid >> 6, lane = tid & 63;
    int wm = wave >> 1;          // entry half
    int wj = wave & 1;           // j half (32 cols)
    int lcol = lane & 15;
    int quad = lane >> 4;

    // A row pointers (gathered tokens), already offset by this lane's k-base
    const unsigned short* aptr[4];
#pragma unroll
    for (int mt = 0; mt < 4; mt++) {
        int m = m0 + wm * 64 + mt * 16 + lcol;
        int row = tok[e * CAP + (m < cnt ? m : m0)];
        aptr[mt] = hb16 + (size_t)(row >> 2) * NH + quad * 8;
    }
    // B row pointers: nt0,1 gate; nt2,3 up
    const float* bptr[4];
    const float* gup_e = gup + (size_t)e * (2 * NI) * NH;
#pragma unroll
    for (int nt = 0; nt < 2; nt++) {
        int j = j0 + wj * 32 + nt * 16 + lcol;
        bptr[nt]     = gup_e + (size_t)j * NH + quad * 8;
        bptr[nt + 2] = gup_e + (size_t)(NI + j) * NH + quad * 8;
    }

    floatx4 acc[4][4];
#pragma unroll
    for (int a = 0; a < 4; a++)
#pragma unroll
        for (int b = 0; b < 4; b++) acc[a][b] = (floatx4){0.f, 0.f, 0.f, 0.f};

#pragma unroll 2
    for (int k = 0; k < NH; k += 32) {
        short8 af[4], bfr[4];
#pragma unroll
        for (int mt = 0; mt < 4; mt++)
            af[mt] = *(const short8*)(aptr[mt] + k);
#pragma unroll
        for (int nt = 0; nt < 4; nt++) {
            float4 lo = *(const float4*)(bptr[nt] + k);
            float4 hi = *(const float4*)(bptr[nt] + k + 4);
            bfr[nt] = cvt_frag(lo, hi);
        }
#pragma unroll
        for (int mt = 0; mt < 4; mt++)
#pragma unroll
            for (int nt = 0; nt < 4; nt++)
                acc[mt][nt] = __builtin_amdgcn_mfma_f32_16x16x32_bf16(
                    af[mt], bfr[nt], acc[mt][nt], 0, 0, 0);
    }

    // epilogue: in-register SiLU fuse (gate nt, up nt+2), bf16 stores
#pragma unroll
    for (int mt = 0; mt < 4; mt++) {
#pragma unroll
        for (int i = 0; i < 4; i++) {
            int m = wm * 64 + mt * 16 + quad * 4 + i;
            if (m0 + m < cnt) {
                int tk = tok[e * CAP + m0 + m];
                unsigned short* hp = hbuf + (size_t)tk * NI + j0 + wj * 32 + lcol;
#pragma unroll
                for (int nt = 0; nt < 2; nt++) {
                    float g = acc[mt][nt][i];
                    float u = acc[mt][nt + 2][i];
                    float h = g / (1.f + __expf(-g)) * u;
                    hp[nt * 16] = bf16_1(h);
                }
            }
        }
    }
}

// ---------------- down + weight-scale + atomic accumulate ----------------
// block tile: 128 entries x 128 H-cols. wave (wm,wn): 64 x 64.
__global__ __launch_bounds__(256, 3) void down_mfma(
    const unsigned short* __restrict__ hbuf,   // [NT*NK][NI] bf16
    const float* __restrict__ down,            // [NE][NH][NI] fp32
    const int* __restrict__ counts,
    const int* __restrict__ tok,
    const float* __restrict__ wgt,
    float* __restrict__ out)                   // [NT][NH] fp32
{
    int e = blockIdx.z;
    int cnt = counts[e]; if (cnt > CAP) cnt = CAP;
    int m0 = blockIdx.y * 128;
    if (m0 >= cnt) return;
    int n0 = blockIdx.x * 128;

    int tid = threadIdx.x;
    int wave = tid >> 6, lane = tid & 63;
    int wm = wave >> 1, wn = wave & 1;
    int lcol = lane & 15;
    int quad = lane >> 4;

    const unsigned short* aptr[4];
#pragma unroll
    for (int mt = 0; mt < 4; mt++) {
        int m = m0 + wm * 64 + mt * 16 + lcol;
        int row = tok[e * CAP + (m < cnt ? m : m0)];
        aptr[mt] = hbuf + (size_t)row * NI + quad * 8;
    }
    const float* bptr[4];
    const float* dwn_e = down + (size_t)e * NH * NI;
#pragma unroll
    for (int nt = 0; nt < 4; nt++) {
        int n = n0 + wn * 64 + nt * 16 + lcol;
        bptr[nt] = dwn_e + (size_t)n * NI + quad * 8;
    }

    floatx4 acc[4][4];
#pragma unroll
    for (int a = 0; a < 4; a++)
#pragma unroll
        for (int b = 0; b < 4; b++) acc[a][b] = (floatx4){0.f, 0.f, 0.f, 0.f};

#pragma unroll 2
    for (int k = 0; k < NI; k += 32) {
        short8 af[4], bfr[4];
#pragma unroll
        for (int mt = 0; mt < 4; mt++)
            af[mt] = *(const short8*)(aptr[mt] + k);
#pragma unroll
        for (int nt = 0; nt < 4; nt++) {
            float4 lo = *(const float4*)(bptr[nt] + k);
            float4 hi = *(const float4*)(bptr[nt] + k + 4);
            bfr[nt] = cvt_frag(lo, hi);
        }
#pragma unroll
        for (int mt = 0; mt < 4; mt++)
#pragma unroll
            for (int nt = 0; nt < 4; nt++)
                acc[mt][nt] = __builtin_amdgcn_mfma_f32_16x16x32_bf16(
                    af[mt], bfr[nt], acc[mt][nt], 0, 0, 0);
    }

#pragma unroll
    for (int mt = 0; mt < 4; mt++)
#pragma unroll
        for (int i = 0; i < 4; i++) {
            int m = wm * 64 + mt * 16 + quad * 4 + i;
            if (m0 + m < cnt) {
                int tk = tok[e * CAP + m0 + m];
                float wl = wgt[e * CAP + m0 + m];
                float* op = out + (size_t)(tk >> 2) * NH + n0 + wn * 64 + lcol;
#pragma unroll
                for (int nt = 0; nt < 4; nt++)
                    atomicAdd(op + nt * 16, acc[mt][nt][i] * wl);
            }
        }
}

extern "C" void kernel_launch(void* const* d_in, const int* in_sizes, int n_in,
                              void* d_out, int out_size, void* d_ws, size_t ws_size,
                              hipStream_t stream) {
    const float* hidden = (const float*)d_in[0];
    const int*   tk_idx = (const int*)d_in[1];
    const float* tk_w   = (const float*)d_in[2];
    const float* gup    = (const float*)d_in[3];
    const float* down   = (const float*)d_in[4];
    float* out = (float*)d_out;

    char* ws = (char*)d_ws;
    size_t off = 0;
    int*            counts = (int*)(ws + off); off += 256;
    int*            tok    = (int*)(ws + off); off += (size_t)NE * CAP * 4;
    float*          wgt    = (float*)(ws + off); off += (size_t)NE * CAP * 4;
    unsigned short* hb16   = (unsigned short*)(ws + off); off += (size_t)NT * NH * 2;      // 4 MB
    unsigned short* hbuf   = (unsigned short*)(ws + off); off += (size_t)NT * NK * NI * 2; // 8.4 MB

    hipMemsetAsync(counts, 0, 256, stream);
    hipMemsetAsync(out, 0, (size_t)NT * NH * sizeof(float), stream);

    route_kernel<<<(NT * NK + 255) / 256, 256, 0, stream>>>(tk_idx, tk_w, counts, tok, wgt);
    cvt_hidden<<<(NT * NH / 8) / 256, 256, 0, stream>>>(hidden, hb16);

    dim3 gridG(NI / 64, CAP / 128, NE);    // (8, 4, 32)
    gateup_mfma<<<gridG, 256, 0, stream>>>(hb16, gup, counts, tok, hbuf);

    dim3 gridD(NH / 128, CAP / 128, NE);   // (8, 4, 32)
    down_mfma<<<gridD, 256, 0, stream>>>(hbuf, down, counts, tok, wgt, out);
}